// Round 4
// baseline (706.016 us; speedup 1.0000x reference)
//
#include <hip/hip_runtime.h>
#include <hip/hip_bf16.h>
#include <math.h>

// Problem constants (from reference setup_inputs)
#define BN  8
#define QN  2048
#define KN  2048
#define FN  512
#define FVN 512

typedef __bf16 bf16x8 __attribute__((ext_vector_type(8)));
typedef __bf16 bf16x4v __attribute__((ext_vector_type(4)));
typedef float  f32x4  __attribute__((ext_vector_type(4)));

__device__ inline bf16x8 pack8(float4 a, float4 b) {
  bf16x8 r;
  r[0] = (__bf16)a.x; r[1] = (__bf16)a.y; r[2] = (__bf16)a.z; r[3] = (__bf16)a.w;
  r[4] = (__bf16)b.x; r[5] = (__bf16)b.y; r[6] = (__bf16)b.z; r[7] = (__bf16)b.w;
  return r;
}

// Async global->LDS, 16B/lane. LDS dest = wave-uniform base + lane*16 (m97).
__device__ __forceinline__ void g2l16(const __bf16* g, __bf16* l) {
  __builtin_amdgcn_global_load_lds(
      (const __attribute__((address_space(1))) void*)g,
      (__attribute__((address_space(3))) void*)l,
      16, 0, 0);
}

// ---------------------------------------------------------------------------
// Kernel 0 (prep): y==0 -> q convert (pre-scaled), y==1 -> k convert,
//                  y==2 -> v transpose to Vt[b, fv, k] bf16, y==3 -> zero sums.
// ---------------------------------------------------------------------------
__global__ __launch_bounds__(256) void prep(
    const float* __restrict__ qm, const float* __restrict__ km,
    const float* __restrict__ vm,
    __bf16* __restrict__ qb, __bf16* __restrict__ kb, __bf16* __restrict__ Vt,
    float* __restrict__ sums) {
  const int tid = threadIdx.x;
  if (blockIdx.y == 0) {
    const size_t idx = ((size_t)blockIdx.x * 256 + tid) * 8;
    const float scale = 0.044194173824159216f;  // 512^-0.5
    float4 a = *(const float4*)(qm + idx);
    float4 b = *(const float4*)(qm + idx + 4);
    a.x *= scale; a.y *= scale; a.z *= scale; a.w *= scale;
    b.x *= scale; b.y *= scale; b.z *= scale; b.w *= scale;
    *(bf16x8*)(qb + idx) = pack8(a, b);
  } else if (blockIdx.y == 1) {
    const size_t idx = ((size_t)blockIdx.x * 256 + tid) * 8;
    float4 a = *(const float4*)(km + idx);
    float4 b = *(const float4*)(km + idx + 4);
    *(bf16x8*)(kb + idx) = pack8(a, b);
  } else if (blockIdx.y == 2) {
    // v transpose: 2048 logical blocks; bx = ((b*8)+fblk)*32 + kblk
    const int bx = blockIdx.x;
    if (bx >= (KN / 64) * (FVN / 64) * BN) return;
    const int b  = bx >> 8;                 // /(32*8)
    const int f0 = ((bx >> 5) & 7) * 64;
    const int k0 = (bx & 31) * 64;
    __shared__ float tile[64][65];
    const int r = tid >> 4;          // 0..15
    const int c = (tid & 15) * 4;    // 0..60
#pragma unroll
    for (int i = 0; i < 4; i++) {
      float4 u = *(const float4*)(vm + ((size_t)b * KN + k0 + r + i * 16) * FVN + f0 + c);
      tile[r + i * 16][c] = u.x; tile[r + i * 16][c + 1] = u.y;
      tile[r + i * 16][c + 2] = u.z; tile[r + i * 16][c + 3] = u.w;
    }
    __syncthreads();
#pragma unroll
    for (int i = 0; i < 4; i++) {
      int fv = r + i * 16;
      bf16x4v w;
      w[0] = (__bf16)tile[c][fv];     w[1] = (__bf16)tile[c + 1][fv];
      w[2] = (__bf16)tile[c + 2][fv]; w[3] = (__bf16)tile[c + 3][fv];
      *(bf16x4v*)(Vt + ((size_t)b * FVN + f0 + fv) * KN + k0 + c) = w;
    }
  } else {
    // zero sums[BN*QN] f32 = 64 KB: 16 blocks x 256 thr x 16B
    if (blockIdx.x < (BN * QN) / 1024) {
      float4 z4; z4.x = 0.f; z4.y = 0.f; z4.z = 0.f; z4.w = 0.f;
      ((float4*)sums)[(size_t)blockIdx.x * 256 + tid] = z4;
    }
  }
}

// ---------------------------------------------------------------------------
// Kernel 1: S[z,q,k] = (bf16) dot(qb[b,q,:], kb[b,k,:])   (scale pre-folded)
// 128x128 tile, BK=64 as two m97-verified [128][32] LDS half-tiles.
// Epilogue accumulates row-sums of exp(S) (f32 accs) into sums[b,q]
// (16-lane shfl reduce -> 1 atomicAdd per row per wave).  [verified r1-r3]
// ---------------------------------------------------------------------------
__global__ __launch_bounds__(256) void gemm_s(
    const __bf16* __restrict__ qb, const __bf16* __restrict__ kb,
    __bf16* __restrict__ Sws, float* __restrict__ sums,
    int b0, int q0, int qchunk) {
  __shared__ __align__(16) __bf16 As[2][128][32];  // 16 KB, k-half h
  __shared__ __align__(16) __bf16 Bs[2][128][32];
  const int tid = threadIdx.x;
  const int lane = tid & 63, wave = tid >> 6;
  const int wq = (wave & 1) * 64, wk = (wave >> 1) * 64;
  const int qt = blockIdx.x * 128, kt = blockIdx.y * 128;
  const int z = blockIdx.z, b = b0 + z;
  __bf16* S = Sws + (size_t)z * qchunk * KN;
  const __bf16* Ab = qb + ((size_t)b * QN + q0 + qt) * FN;
  const __bf16* Bb = kb + ((size_t)b * KN + kt) * FN;
  const int srow = lane >> 2;         // 0..15 within 16-row group
  const int scol = (lane & 3) * 8;    // bf16 col within 32
  const int r = lane & 15, quad = lane >> 4;
  f32x4 acc[4][4] = {};
  for (int f0 = 0; f0 < FN; f0 += 64) {
    __syncthreads();                  // prev-iter frag reads done
#pragma unroll
    for (int h = 0; h < 2; h++) {
      const int co = f0 + h * 32 + scol;
      g2l16(Ab + (size_t)(wave * 32 + srow) * FN + co,      &As[h][wave * 32][0]);
      g2l16(Ab + (size_t)(wave * 32 + 16 + srow) * FN + co, &As[h][wave * 32 + 16][0]);
      g2l16(Bb + (size_t)(wave * 32 + srow) * FN + co,      &Bs[h][wave * 32][0]);
      g2l16(Bb + (size_t)(wave * 32 + 16 + srow) * FN + co, &Bs[h][wave * 32 + 16][0]);
    }
    __syncthreads();                  // vmcnt drain + visibility
#pragma unroll
    for (int h = 0; h < 2; h++) {
      bf16x8 af[4], bf[4];
#pragma unroll
      for (int i = 0; i < 4; i++) af[i] = *(bf16x8*)&As[h][wq + i * 16 + r][quad * 8];
#pragma unroll
      for (int j = 0; j < 4; j++) bf[j] = *(bf16x8*)&Bs[h][wk + j * 16 + r][quad * 8];
#pragma unroll
      for (int i = 0; i < 4; i++)
#pragma unroll
        for (int j = 0; j < 4; j++)
          acc[i][j] = __builtin_amdgcn_mfma_f32_16x16x32_bf16(af[i], bf[j], acc[i][j], 0, 0, 0);
    }
  }
  // C/D layout (m89-verified): col = lane&15 (=k), row = quad*4+reg (=q)
#pragma unroll
  for (int i = 0; i < 4; i++)
#pragma unroll
    for (int j = 0; j < 4; j++)
#pragma unroll
      for (int t = 0; t < 4; t++) {
        int qq = qt + wq + i * 16 + quad * 4 + t;
        int kk = kt + wk + j * 16 + r;
        S[(size_t)qq * KN + kk] = (__bf16)acc[i][j][t];
      }
  // Row-sum of exp over this block's 64 k-cols per wave (denominator is
  // UNMASKED sum over all k; partials from the 16 kt-blocks accumulate).
#pragma unroll
  for (int i = 0; i < 4; i++)
#pragma unroll
    for (int t = 0; t < 4; t++) {
      float part = 0.f;
#pragma unroll
      for (int j = 0; j < 4; j++) part += __expf(acc[i][j][t]);
      part += __shfl_xor(part, 1);
      part += __shfl_xor(part, 2);
      part += __shfl_xor(part, 4);
      part += __shfl_xor(part, 8);
      if (r == 0)
        atomicAdd(&sums[(size_t)b * QN + q0 + qt + wq + i * 16 + quad * 4 + t], part);
    }
}

// ---------------------------------------------------------------------------
// Kernel 2 (fused W-build + PV GEMM, replaces softmax_w + gemm_w):
//   out[b,q,:] = sum_k [attn ? 0 : (exp(S)*inv - (alibi ? 0 : dist*bs))] * Vt[:,k]
// Barrier-free, LDS-free. Tile 32q x 512fv, 256 thr, 4 waves
// (wave = q-half x fv-half). A-frag (W) built in registers from global
// S/mask/coord loads in exact MFMA lane layout (row = wq+r, k = quad*8+h*32);
// mask latency hides under 32 MFMA/step + co-resident waves (no vmcnt(0)
// drains anywhere). B-frag read directly from L2-resident Vt (2 MB/batch).
// Chunked XCD swizzle pins batch z to XCD z (nwg=512 -> cpx=64=nqt).
// W never touches HBM (-134 MB round-trip vs 3-kernel structure).
// ---------------------------------------------------------------------------
__global__ __launch_bounds__(256) void gemm_wd(
    const __bf16* __restrict__ Sws, const __bf16* __restrict__ Vt,
    const float* __restrict__ sums,
    const float* __restrict__ cq, const float* __restrict__ ck,
    const int* __restrict__ attn, const int* __restrict__ alibi,
    const float* __restrict__ bsp, float* __restrict__ out,
    int b0, int q0, int qchunk) {
  const int nqt = qchunk / 32;
  const int nwg = gridDim.x;
  int work = blockIdx.x;
  if ((nwg & 7) == 0)                       // bijective chunked XCD swizzle
    work = (work & 7) * (nwg >> 3) + (work >> 3);
  const int z = work / nqt, qt = work % nqt;
  const int b = b0 + z;
  const int tid = threadIdx.x;
  const int lane = tid & 63;
  const int wave = tid >> 6;
  const int r = lane & 15, quad = lane >> 4;
  const int wq = (wave >> 1) * 16;          // q-half (0/16)
  const int wf = (wave & 1) * 256;          // fv-half (0/256)
  const int qrow_l = qt * 32 + wq + r;      // lane's A-row (local q)
  const int qg = q0 + qrow_l;               // global q
  const __bf16* Srow = Sws + ((size_t)z * qchunk + qrow_l) * KN;
  const int* arow = attn + ((size_t)b * QN + qg) * KN;
  const int* lrow = alibi + ((size_t)b * QN + qg) * KN;
  const float* ckb = ck + (size_t)b * KN * 2;
  const __bf16* Vb = Vt + ((size_t)b * FVN + wf + r) * KN;  // lane's B-row base
  const float inv = 1.0f / sums[(size_t)b * QN + qg];       // row-uniform per lane
  const float qx = cq[((size_t)b * QN + qg) * 2 + 0];
  const float qy = cq[((size_t)b * QN + qg) * 2 + 1];
  const float bs = bsp[0];
  f32x4 acc[16] = {};
  for (int k0 = 0; k0 < KN; k0 += 64) {
#pragma unroll
    for (int h = 0; h < 2; h++) {
      const int kk = k0 + h * 32 + quad * 8;   // lane's 8-k chunk
      bf16x8 s8 = *(const bf16x8*)(Srow + kk);
      int4 am0 = *(const int4*)(arow + kk), am1 = *(const int4*)(arow + kk + 4);
      int4 al0 = *(const int4*)(lrow + kk), al1 = *(const int4*)(lrow + kk + 4);
      float4 c0 = *(const float4*)(ckb + (size_t)kk * 2);
      float4 c1 = *(const float4*)(ckb + (size_t)kk * 2 + 4);
      float4 c2 = *(const float4*)(ckb + (size_t)kk * 2 + 8);
      float4 c3 = *(const float4*)(ckb + (size_t)kk * 2 + 12);
      int   am[8] = {am0.x, am0.y, am0.z, am0.w, am1.x, am1.y, am1.z, am1.w};
      int   al[8] = {al0.x, al0.y, al0.z, al0.w, al1.x, al1.y, al1.z, al1.w};
      float kx[8] = {c0.x, c0.z, c1.x, c1.z, c2.x, c2.z, c3.x, c3.z};
      float ky[8] = {c0.y, c0.w, c1.y, c1.w, c2.y, c2.w, c3.y, c3.w};
      bf16x8 w8;
#pragma unroll
      for (int j = 0; j < 8; j++) {
        float p = __expf((float)s8[j]) * inv;
        float dx = qx - kx[j], dy = qy - ky[j];
        float sd = al[j] ? 0.f : sqrtf(dx * dx + dy * dy) * bs;
        w8[j] = (__bf16)(am[j] ? 0.f : (p - sd));
      }
#pragma unroll
      for (int j = 0; j < 16; j++) {
        bf16x8 bv = *(const bf16x8*)(Vb + (size_t)j * 16 * KN + kk);
        acc[j] = __builtin_amdgcn_mfma_f32_16x16x32_bf16(w8, bv, acc[j], 0, 0, 0);
      }
    }
  }
  // C/D layout (m89-verified): row = quad*4+t (=q), col = r (=fv within frag)
#pragma unroll
  for (int j = 0; j < 16; j++)
#pragma unroll
    for (int t = 0; t < 4; t++) {
      int qq = q0 + qt * 32 + wq + quad * 4 + t;
      int fv = wf + j * 16 + r;
      out[((size_t)b * QN + qq) * FVN + fv] = acc[j][t];
    }
}

// ---------------------------------------------------------------------------
extern "C" void kernel_launch(void* const* d_in, const int* in_sizes, int n_in,
                              void* d_out, int out_size, void* d_ws, size_t ws_size,
                              hipStream_t stream) {
  (void)in_sizes; (void)n_in; (void)out_size;
  const float* qm   = (const float*)d_in[0];
  const float* km   = (const float*)d_in[1];
  const float* vm   = (const float*)d_in[2];
  const float* cq   = (const float*)d_in[3];
  const float* ck   = (const float*)d_in[4];
  const int*   attn = (const int*)d_in[5];
  const int*   alibi= (const int*)d_in[6];
  const float* bsp  = (const float*)d_in[7];
  float* out = (float*)d_out;

  // ws layout: [qb][kb][Vt][sums f32] fixed + [S: nb*qc*KN bf16]
  __bf16* qb  = (__bf16*)d_ws;
  __bf16* kb  = qb + (size_t)BN * QN * FN;
  __bf16* Vt  = kb + (size_t)BN * KN * FN;
  float*  sums = (float*)(Vt + (size_t)BN * FVN * KN);
  __bf16* Sws = (__bf16*)(sums + (size_t)BN * QN);
  const size_t fixed = ((size_t)BN * QN * FN + (size_t)BN * KN * FN +
                        (size_t)BN * FVN * KN) * 2 + (size_t)BN * QN * 4;
  int nb = BN, qc = QN;
  while (nb > 1 && fixed + (size_t)nb * qc * KN * 2 > ws_size) nb >>= 1;
  while (qc > 128 && fixed + (size_t)nb * qc * KN * 2 > ws_size) qc >>= 1;

  prep<<<dim3((BN * QN * FN) / 2048, 4), 256, 0, stream>>>(qm, km, vm, qb, kb, Vt, sums);
  for (int b0 = 0; b0 < BN; b0 += nb) {
    for (int q0 = 0; q0 < QN; q0 += qc) {
      gemm_s<<<dim3(qc / 128, KN / 128, nb), 256, 0, stream>>>(qb, kb, Sws, sums, b0, q0, qc);
      gemm_wd<<<dim3(nb * (qc / 32)), 256, 0, stream>>>(Sws, Vt, sums, cq, ck, attn,
                                                        alibi, bsp, out, b0, q0, qc);
    }
  }
}

// Round 6
// 547.477 us; speedup vs baseline: 1.2896x; 1.2896x over previous
//
#include <hip/hip_runtime.h>
#include <hip/hip_bf16.h>
#include <math.h>

// Problem constants (from reference setup_inputs)
#define BN  8
#define QN  2048
#define KN  2048
#define FN  512
#define FVN 512

typedef __bf16 bf16x8 __attribute__((ext_vector_type(8)));
typedef __bf16 bf16x4v __attribute__((ext_vector_type(4)));
typedef float  f32x4  __attribute__((ext_vector_type(4)));

__device__ inline bf16x8 pack8(float4 a, float4 b) {
  bf16x8 r;
  r[0] = (__bf16)a.x; r[1] = (__bf16)a.y; r[2] = (__bf16)a.z; r[3] = (__bf16)a.w;
  r[4] = (__bf16)b.x; r[5] = (__bf16)b.y; r[6] = (__bf16)b.z; r[7] = (__bf16)b.w;
  return r;
}

// Async global->LDS, 16B/lane. LDS dest = wave-uniform base + lane*16 (m97).
__device__ __forceinline__ void g2l16(const __bf16* g, __bf16* l) {
  __builtin_amdgcn_global_load_lds(
      (const __attribute__((address_space(1))) void*)g,
      (__attribute__((address_space(3))) void*)l,
      16, 0, 0);
}

// ---------------------------------------------------------------------------
// Kernel 0 (prep): y==0 -> q convert (pre-scaled), y==1 -> k convert,
//                  y==2 -> v transpose to Vt[b, fv, k] bf16, y==3 -> zero sums.
// ---------------------------------------------------------------------------
__global__ __launch_bounds__(256) void prep(
    const float* __restrict__ qm, const float* __restrict__ km,
    const float* __restrict__ vm,
    __bf16* __restrict__ qb, __bf16* __restrict__ kb, __bf16* __restrict__ Vt,
    float* __restrict__ sums) {
  const int tid = threadIdx.x;
  if (blockIdx.y == 0) {
    const size_t idx = ((size_t)blockIdx.x * 256 + tid) * 8;
    const float scale = 0.044194173824159216f;  // 512^-0.5
    float4 a = *(const float4*)(qm + idx);
    float4 b = *(const float4*)(qm + idx + 4);
    a.x *= scale; a.y *= scale; a.z *= scale; a.w *= scale;
    b.x *= scale; b.y *= scale; b.z *= scale; b.w *= scale;
    *(bf16x8*)(qb + idx) = pack8(a, b);
  } else if (blockIdx.y == 1) {
    const size_t idx = ((size_t)blockIdx.x * 256 + tid) * 8;
    float4 a = *(const float4*)(km + idx);
    float4 b = *(const float4*)(km + idx + 4);
    *(bf16x8*)(kb + idx) = pack8(a, b);
  } else if (blockIdx.y == 2) {
    // v transpose: 2048 logical blocks; bx = ((b*8)+fblk)*32 + kblk
    const int bx = blockIdx.x;
    if (bx >= (KN / 64) * (FVN / 64) * BN) return;
    const int b  = bx >> 8;                 // /(32*8)
    const int f0 = ((bx >> 5) & 7) * 64;
    const int k0 = (bx & 31) * 64;
    __shared__ float tile[64][65];
    const int r = tid >> 4;          // 0..15
    const int c = (tid & 15) * 4;    // 0..60
#pragma unroll
    for (int i = 0; i < 4; i++) {
      float4 u = *(const float4*)(vm + ((size_t)b * KN + k0 + r + i * 16) * FVN + f0 + c);
      tile[r + i * 16][c] = u.x; tile[r + i * 16][c + 1] = u.y;
      tile[r + i * 16][c + 2] = u.z; tile[r + i * 16][c + 3] = u.w;
    }
    __syncthreads();
#pragma unroll
    for (int i = 0; i < 4; i++) {
      int fv = r + i * 16;
      bf16x4v w;
      w[0] = (__bf16)tile[c][fv];     w[1] = (__bf16)tile[c + 1][fv];
      w[2] = (__bf16)tile[c + 2][fv]; w[3] = (__bf16)tile[c + 3][fv];
      *(bf16x4v*)(Vt + ((size_t)b * FVN + f0 + fv) * KN + k0 + c) = w;
    }
  } else {
    // zero sums[BN*QN] f32 = 64 KB: 16 blocks x 256 thr x 16B
    if (blockIdx.x < (BN * QN) / 1024) {
      float4 z4; z4.x = 0.f; z4.y = 0.f; z4.z = 0.f; z4.w = 0.f;
      ((float4*)sums)[(size_t)blockIdx.x * 256 + tid] = z4;
    }
  }
}

// ---------------------------------------------------------------------------
// Kernel 1: S[z,q,k] = (bf16) dot(qb[b,q,:], kb[b,k,:])   (scale pre-folded)
// 128x128 tile, BK=64 as two m97-verified [128][32] LDS half-tiles.
// Epilogue accumulates row-sums of exp(S) (f32 accs) into sums[b,q]
// (16-lane shfl reduce -> 1 atomicAdd per row per wave).  [verified r1-r4]
// ---------------------------------------------------------------------------
__global__ __launch_bounds__(256) void gemm_s(
    const __bf16* __restrict__ qb, const __bf16* __restrict__ kb,
    __bf16* __restrict__ Sws, float* __restrict__ sums,
    int b0, int q0, int qchunk) {
  __shared__ __align__(16) __bf16 As[2][128][32];  // 16 KB, k-half h
  __shared__ __align__(16) __bf16 Bs[2][128][32];
  const int tid = threadIdx.x;
  const int lane = tid & 63, wave = tid >> 6;
  const int wq = (wave & 1) * 64, wk = (wave >> 1) * 64;
  const int qt = blockIdx.x * 128, kt = blockIdx.y * 128;
  const int z = blockIdx.z, b = b0 + z;
  __bf16* S = Sws + (size_t)z * qchunk * KN;
  const __bf16* Ab = qb + ((size_t)b * QN + q0 + qt) * FN;
  const __bf16* Bb = kb + ((size_t)b * KN + kt) * FN;
  const int srow = lane >> 2;         // 0..15 within 16-row group
  const int scol = (lane & 3) * 8;    // bf16 col within 32
  const int r = lane & 15, quad = lane >> 4;
  f32x4 acc[4][4] = {};
  for (int f0 = 0; f0 < FN; f0 += 64) {
    __syncthreads();                  // prev-iter frag reads done
#pragma unroll
    for (int h = 0; h < 2; h++) {
      const int co = f0 + h * 32 + scol;
      g2l16(Ab + (size_t)(wave * 32 + srow) * FN + co,      &As[h][wave * 32][0]);
      g2l16(Ab + (size_t)(wave * 32 + 16 + srow) * FN + co, &As[h][wave * 32 + 16][0]);
      g2l16(Bb + (size_t)(wave * 32 + srow) * FN + co,      &Bs[h][wave * 32][0]);
      g2l16(Bb + (size_t)(wave * 32 + 16 + srow) * FN + co, &Bs[h][wave * 32 + 16][0]);
    }
    __syncthreads();                  // vmcnt drain + visibility
#pragma unroll
    for (int h = 0; h < 2; h++) {
      bf16x8 af[4], bf[4];
#pragma unroll
      for (int i = 0; i < 4; i++) af[i] = *(bf16x8*)&As[h][wq + i * 16 + r][quad * 8];
#pragma unroll
      for (int j = 0; j < 4; j++) bf[j] = *(bf16x8*)&Bs[h][wk + j * 16 + r][quad * 8];
#pragma unroll
      for (int i = 0; i < 4; i++)
#pragma unroll
        for (int j = 0; j < 4; j++)
          acc[i][j] = __builtin_amdgcn_mfma_f32_16x16x32_bf16(af[i], bf[j], acc[i][j], 0, 0, 0);
    }
  }
  // C/D layout (m89-verified): col = lane&15 (=k), row = quad*4+reg (=q)
#pragma unroll
  for (int i = 0; i < 4; i++)
#pragma unroll
    for (int j = 0; j < 4; j++)
#pragma unroll
      for (int t = 0; t < 4; t++) {
        int qq = qt + wq + i * 16 + quad * 4 + t;
        int kk = kt + wk + j * 16 + r;
        S[(size_t)qq * KN + kk] = (__bf16)acc[i][j][t];
      }
  // Row-sum of exp over this block's 64 k-cols per wave (denominator is
  // UNMASKED sum over all k; partials from the 16 kt-blocks accumulate).
#pragma unroll
  for (int i = 0; i < 4; i++)
#pragma unroll
    for (int t = 0; t < 4; t++) {
      float part = 0.f;
#pragma unroll
      for (int j = 0; j < 4; j++) part += __expf(acc[i][j][t]);
      part += __shfl_xor(part, 1);
      part += __shfl_xor(part, 2);
      part += __shfl_xor(part, 4);
      part += __shfl_xor(part, 8);
      if (r == 0)
        atomicAdd(&sums[(size_t)b * QN + q0 + qt + wq + i * 16 + quad * 4 + t], part);
    }
}

// ---------------------------------------------------------------------------
// Kernel 2 (fused W-build + PV GEMM inside the VERIFIED LDS/barrier GEMM
// structure; replaces softmax_w + gemm_w):
//   out[b,q,:] = sum_k [attn ? 0 : (exp(S)*inv - (alibi ? 0 : dist*bs))]*Vt[:,k]
// Tile 64q x 128fv, 256 thr, grid 512 blocks (=2/CU -> m114 cross-block
// overlap). Bs staged via verbatim g2l16 pattern; As BUILT in registers:
// thread (row=tid>>2, c4=tid&3) loads S(32B)+masks(128B) for 16 k, computes
// W, ds_write to As. T14 issue-early: next step's S/mask loads issue right
// after the drain barrier, hiding under the MFMA phase.
// Wave tile 32q x 64fv = acc[2][4] (2 q-frags x 4 fv-frags)  [r5 bug: was
// acc[2][2] -> half the fv columns never written].
// W never touches HBM (-134 MB round-trip); mask stream hides under GEMM.
// ---------------------------------------------------------------------------
__global__ __launch_bounds__(256) void gemm_wf(
    const __bf16* __restrict__ Sws, const __bf16* __restrict__ Vt,
    const float* __restrict__ sums,
    const float* __restrict__ cq, const float* __restrict__ ck,
    const int* __restrict__ attn, const int* __restrict__ alibi,
    const float* __restrict__ bsp, float* __restrict__ out,
    int b0, int q0, int qchunk) {
  __shared__ __align__(16) __bf16 As[2][64][32];   // [h][q][k-half]  8 KB
  __shared__ __align__(16) __bf16 Bs[2][128][32];  // [h][fv][k-half] 16 KB
  __shared__ float ckx[KN], cky[KN];               // 16 KB
  const int tid = threadIdx.x;
  const int lane = tid & 63, wave = tid >> 6;
  const int qt = blockIdx.x * 64, ft = blockIdx.y * 128;
  const int z = blockIdx.z, b = b0 + z;
  // --- A-build mapping: thread = (row 0..63, c4 = 16-k chunk 0..3) ---
  const int arow_l = tid >> 2;
  const int c4 = tid & 3;
  const int qg = q0 + qt + arow_l;
  const __bf16* Srow = Sws + ((size_t)z * qchunk + qt + arow_l) * KN;
  const int* amrow = attn + ((size_t)b * QN + qg) * KN;
  const int* alrow = alibi + ((size_t)b * QN + qg) * KN;
  const float inv = 1.0f / sums[(size_t)b * QN + qg];
  const float qx = cq[((size_t)b * QN + qg) * 2 + 0];
  const float qy = cq[((size_t)b * QN + qg) * 2 + 1];
  const float bs = bsp[0];
  // --- B-stage mapping (verbatim from verified gemm_w) ---
  const int srow = lane >> 2, scol = (lane & 3) * 8;
  const __bf16* Bb = Vt + ((size_t)b * FVN + ft) * KN;
  // --- MFMA mapping: 4 waves = 2(q) x 2(fv); wave tile 32q x 64fv ---
  const int r = lane & 15, quad = lane >> 4;
  const int wq = (wave & 1) * 32, wf = (wave >> 1) * 64;
  // --- stage k-coords to LDS once (deinterleaved) ---
  const float* ckb = ck + (size_t)b * KN * 2;
  for (int i = tid; i < KN / 2; i += 256) {
    float4 u = *(const float4*)(ckb + (size_t)i * 4);
    ckx[2 * i] = u.x;     cky[2 * i] = u.y;
    ckx[2 * i + 1] = u.z; cky[2 * i + 1] = u.w;
  }
  f32x4 acc[2][4] = {};
  // --- prologue reg prefetch for k0 = 0 ---
  bf16x8 s8a, s8b; int4 amv[4], alv[4];
  {
    const int kk = c4 * 16;
    s8a = *(const bf16x8*)(Srow + kk);
    s8b = *(const bf16x8*)(Srow + kk + 8);
#pragma unroll
    for (int i = 0; i < 4; i++) {
      amv[i] = *(const int4*)(amrow + kk + i * 4);
      alv[i] = *(const int4*)(alrow + kk + i * 4);
    }
  }
  __syncthreads();   // ck staging visible
  for (int k0 = 0; k0 < KN; k0 += 64) {
    // --- W-build from prefetched regs -> ds_write As ---
    {
      const int kk = k0 + c4 * 16;
      float kxv[16], kyv[16];
#pragma unroll
      for (int j4 = 0; j4 < 4; j4++) {
        float4 x4 = *(const float4*)&ckx[kk + j4 * 4];
        float4 y4 = *(const float4*)&cky[kk + j4 * 4];
        kxv[j4 * 4 + 0] = x4.x; kxv[j4 * 4 + 1] = x4.y;
        kxv[j4 * 4 + 2] = x4.z; kxv[j4 * 4 + 3] = x4.w;
        kyv[j4 * 4 + 0] = y4.x; kyv[j4 * 4 + 1] = y4.y;
        kyv[j4 * 4 + 2] = y4.z; kyv[j4 * 4 + 3] = y4.w;
      }
      int amA[16] = {amv[0].x, amv[0].y, amv[0].z, amv[0].w,
                     amv[1].x, amv[1].y, amv[1].z, amv[1].w,
                     amv[2].x, amv[2].y, amv[2].z, amv[2].w,
                     amv[3].x, amv[3].y, amv[3].z, amv[3].w};
      int alA[16] = {alv[0].x, alv[0].y, alv[0].z, alv[0].w,
                     alv[1].x, alv[1].y, alv[1].z, alv[1].w,
                     alv[2].x, alv[2].y, alv[2].z, alv[2].w,
                     alv[3].x, alv[3].y, alv[3].z, alv[3].w};
      bf16x8 w0, w1;
#pragma unroll
      for (int j = 0; j < 16; j++) {
        float sv = (j < 8) ? (float)s8a[j] : (float)s8b[j - 8];
        float p = __expf(sv) * inv;
        float dx = qx - kxv[j], dy = qy - kyv[j];
        float sd = alA[j] ? 0.f : sqrtf(dx * dx + dy * dy) * bs;
        float w = amA[j] ? 0.f : (p - sd);
        if (j < 8) w0[j] = (__bf16)w; else w1[j - 8] = (__bf16)w;
      }
      const int h = c4 >> 1, off = (c4 & 1) * 16;
      *(bf16x8*)&As[h][arow_l][off]     = w0;
      *(bf16x8*)&As[h][arow_l][off + 8] = w1;
    }
    // --- B stage (g2l16, verbatim pattern) ---
#pragma unroll
    for (int h = 0; h < 2; h++) {
      const int co = k0 + h * 32 + scol;
      g2l16(Bb + (size_t)(wave * 32 + srow) * KN + co,      &Bs[h][wave * 32][0]);
      g2l16(Bb + (size_t)(wave * 32 + 16 + srow) * KN + co, &Bs[h][wave * 32 + 16][0]);
    }
    __syncthreads();   // drain ds_write (lgkm) + g2l (vmcnt), visibility
    // --- T14 issue-early: next step's S/mask loads under the MFMA phase ---
    if (k0 + 64 < KN) {
      const int kk = k0 + 64 + c4 * 16;
      s8a = *(const bf16x8*)(Srow + kk);
      s8b = *(const bf16x8*)(Srow + kk + 8);
#pragma unroll
      for (int i = 0; i < 4; i++) {
        amv[i] = *(const int4*)(amrow + kk + i * 4);
        alv[i] = *(const int4*)(alrow + kk + i * 4);
      }
    }
    // --- MFMA phase: 2 q-frags x 4 fv-frags per wave ---
#pragma unroll
    for (int h = 0; h < 2; h++) {
      bf16x8 af[2], bf[4];
#pragma unroll
      for (int i = 0; i < 2; i++) af[i] = *(bf16x8*)&As[h][wq + i * 16 + r][quad * 8];
#pragma unroll
      for (int j = 0; j < 4; j++) bf[j] = *(bf16x8*)&Bs[h][wf + j * 16 + r][quad * 8];
#pragma unroll
      for (int i = 0; i < 2; i++)
#pragma unroll
        for (int j = 0; j < 4; j++)
          acc[i][j] = __builtin_amdgcn_mfma_f32_16x16x32_bf16(af[i], bf[j], acc[i][j], 0, 0, 0);
    }
    __syncthreads();   // all waves done reading As/Bs before next overwrite
  }
  // C/D layout (m89-verified): row = quad*4+t (=q), col = r (=fv)
#pragma unroll
  for (int i = 0; i < 2; i++)
#pragma unroll
    for (int j = 0; j < 4; j++)
#pragma unroll
      for (int t = 0; t < 4; t++) {
        int qq = q0 + qt + wq + i * 16 + quad * 4 + t;
        int fv = ft + wf + j * 16 + r;
        out[((size_t)b * QN + qq) * FVN + fv] = acc[i][j][t];
      }
}

// ---------------------------------------------------------------------------
extern "C" void kernel_launch(void* const* d_in, const int* in_sizes, int n_in,
                              void* d_out, int out_size, void* d_ws, size_t ws_size,
                              hipStream_t stream) {
  (void)in_sizes; (void)n_in; (void)out_size;
  const float* qm   = (const float*)d_in[0];
  const float* km   = (const float*)d_in[1];
  const float* vm   = (const float*)d_in[2];
  const float* cq   = (const float*)d_in[3];
  const float* ck   = (const float*)d_in[4];
  const int*   attn = (const int*)d_in[5];
  const int*   alibi= (const int*)d_in[6];
  const float* bsp  = (const float*)d_in[7];
  float* out = (float*)d_out;

  // ws layout: [qb][kb][Vt][sums f32] fixed + [S: nb*qc*KN bf16]
  __bf16* qb  = (__bf16*)d_ws;
  __bf16* kb  = qb + (size_t)BN * QN * FN;
  __bf16* Vt  = kb + (size_t)BN * KN * FN;
  float*  sums = (float*)(Vt + (size_t)BN * FVN * KN);
  __bf16* Sws = (__bf16*)(sums + (size_t)BN * QN);
  const size_t fixed = ((size_t)BN * QN * FN + (size_t)BN * KN * FN +
                        (size_t)BN * FVN * KN) * 2 + (size_t)BN * QN * 4;
  int nb = BN, qc = QN;
  while (nb > 1 && fixed + (size_t)nb * qc * KN * 2 > ws_size) nb >>= 1;
  while (qc > 128 && fixed + (size_t)nb * qc * KN * 2 > ws_size) qc >>= 1;

  prep<<<dim3((BN * QN * FN) / 2048, 4), 256, 0, stream>>>(qm, km, vm, qb, kb, Vt, sums);
  for (int b0 = 0; b0 < BN; b0 += nb) {
    for (int q0 = 0; q0 < QN; q0 += qc) {
      gemm_s<<<dim3(qc / 128, KN / 128, nb), 256, 0, stream>>>(qb, kb, Sws, sums, b0, q0, qc);
      gemm_wf<<<dim3(qc / 64, FVN / 128, nb), 256, 0, stream>>>(Sws, Vt, sums, cq, ck,
                                                                attn, alibi, bsp, out,
                                                                b0, q0, qc);
    }
  }
}

// Round 7
// 477.176 us; speedup vs baseline: 1.4796x; 1.1473x over previous
//
#include <hip/hip_runtime.h>
#include <hip/hip_bf16.h>
#include <math.h>

// Problem constants (from reference setup_inputs)
#define BN  8
#define QN  2048
#define KN  2048
#define FN  512
#define FVN 512

typedef __bf16 bf16x8 __attribute__((ext_vector_type(8)));
typedef __bf16 bf16x4v __attribute__((ext_vector_type(4)));
typedef float  f32x4  __attribute__((ext_vector_type(4)));

__device__ inline bf16x8 pack8(float4 a, float4 b) {
  bf16x8 r;
  r[0] = (__bf16)a.x; r[1] = (__bf16)a.y; r[2] = (__bf16)a.z; r[3] = (__bf16)a.w;
  r[4] = (__bf16)b.x; r[5] = (__bf16)b.y; r[6] = (__bf16)b.z; r[7] = (__bf16)b.w;
  return r;
}

// Async global->LDS, 16B/lane. LDS dest = wave-uniform base + lane*16 (m97).
__device__ __forceinline__ void g2l16(const __bf16* g, __bf16* l) {
  __builtin_amdgcn_global_load_lds(
      (const __attribute__((address_space(1))) void*)g,
      (__attribute__((address_space(3))) void*)l,
      16, 0, 0);
}
__device__ __forceinline__ void g2l16v(const void* g, void* l) {
  __builtin_amdgcn_global_load_lds(
      (const __attribute__((address_space(1))) void*)g,
      (__attribute__((address_space(3))) void*)l,
      16, 0, 0);
}

// ---------------------------------------------------------------------------
// Kernel 0 (prep): y==0 -> q convert (pre-scaled), y==1 -> k convert,
//                  y==2 -> v transpose to Vt[b, fv, k] bf16, y==3 -> zero sums.
// ---------------------------------------------------------------------------
__global__ __launch_bounds__(256) void prep(
    const float* __restrict__ qm, const float* __restrict__ km,
    const float* __restrict__ vm,
    __bf16* __restrict__ qb, __bf16* __restrict__ kb, __bf16* __restrict__ Vt,
    float* __restrict__ sums) {
  const int tid = threadIdx.x;
  if (blockIdx.y == 0) {
    const size_t idx = ((size_t)blockIdx.x * 256 + tid) * 8;
    const float scale = 0.044194173824159216f;  // 512^-0.5
    float4 a = *(const float4*)(qm + idx);
    float4 b = *(const float4*)(qm + idx + 4);
    a.x *= scale; a.y *= scale; a.z *= scale; a.w *= scale;
    b.x *= scale; b.y *= scale; b.z *= scale; b.w *= scale;
    *(bf16x8*)(qb + idx) = pack8(a, b);
  } else if (blockIdx.y == 1) {
    const size_t idx = ((size_t)blockIdx.x * 256 + tid) * 8;
    float4 a = *(const float4*)(km + idx);
    float4 b = *(const float4*)(km + idx + 4);
    *(bf16x8*)(kb + idx) = pack8(a, b);
  } else if (blockIdx.y == 2) {
    // v transpose: 2048 logical blocks; bx = ((b*8)+fblk)*32 + kblk
    const int bx = blockIdx.x;
    if (bx >= (KN / 64) * (FVN / 64) * BN) return;
    const int b  = bx >> 8;                 // /(32*8)
    const int f0 = ((bx >> 5) & 7) * 64;
    const int k0 = (bx & 31) * 64;
    __shared__ float tile[64][65];
    const int r = tid >> 4;          // 0..15
    const int c = (tid & 15) * 4;    // 0..60
#pragma unroll
    for (int i = 0; i < 4; i++) {
      float4 u = *(const float4*)(vm + ((size_t)b * KN + k0 + r + i * 16) * FVN + f0 + c);
      tile[r + i * 16][c] = u.x; tile[r + i * 16][c + 1] = u.y;
      tile[r + i * 16][c + 2] = u.z; tile[r + i * 16][c + 3] = u.w;
    }
    __syncthreads();
#pragma unroll
    for (int i = 0; i < 4; i++) {
      int fv = r + i * 16;
      bf16x4v w;
      w[0] = (__bf16)tile[c][fv];     w[1] = (__bf16)tile[c + 1][fv];
      w[2] = (__bf16)tile[c + 2][fv]; w[3] = (__bf16)tile[c + 3][fv];
      *(bf16x4v*)(Vt + ((size_t)b * FVN + f0 + fv) * KN + k0 + c) = w;
    }
  } else {
    // zero sums[BN*QN] f32 = 64 KB: 16 blocks x 256 thr x 16B
    if (blockIdx.x < (BN * QN) / 1024) {
      float4 z4; z4.x = 0.f; z4.y = 0.f; z4.z = 0.f; z4.w = 0.f;
      ((float4*)sums)[(size_t)blockIdx.x * 256 + tid] = z4;
    }
  }
}

// ---------------------------------------------------------------------------
// Kernel 1: S[z,q,k] = (bf16) dot(qb[b,q,:], kb[b,k,:])   (scale pre-folded)
// 128x128 tile, BK=64 as two m97-verified [128][32] LDS half-tiles.
// Epilogue accumulates row-sums of exp(S) (f32 accs) into sums[b,q]
// (16-lane shfl reduce -> 1 atomicAdd per row per wave).  [verified r1-r6]
// ---------------------------------------------------------------------------
__global__ __launch_bounds__(256) void gemm_s(
    const __bf16* __restrict__ qb, const __bf16* __restrict__ kb,
    __bf16* __restrict__ Sws, float* __restrict__ sums,
    int b0, int q0, int qchunk) {
  __shared__ __align__(16) __bf16 As[2][128][32];  // 16 KB, k-half h
  __shared__ __align__(16) __bf16 Bs[2][128][32];
  const int tid = threadIdx.x;
  const int lane = tid & 63, wave = tid >> 6;
  const int wq = (wave & 1) * 64, wk = (wave >> 1) * 64;
  const int qt = blockIdx.x * 128, kt = blockIdx.y * 128;
  const int z = blockIdx.z, b = b0 + z;
  __bf16* S = Sws + (size_t)z * qchunk * KN;
  const __bf16* Ab = qb + ((size_t)b * QN + q0 + qt) * FN;
  const __bf16* Bb = kb + ((size_t)b * KN + kt) * FN;
  const int srow = lane >> 2;         // 0..15 within 16-row group
  const int scol = (lane & 3) * 8;    // bf16 col within 32
  const int r = lane & 15, quad = lane >> 4;
  f32x4 acc[4][4] = {};
  for (int f0 = 0; f0 < FN; f0 += 64) {
    __syncthreads();                  // prev-iter frag reads done
#pragma unroll
    for (int h = 0; h < 2; h++) {
      const int co = f0 + h * 32 + scol;
      g2l16(Ab + (size_t)(wave * 32 + srow) * FN + co,      &As[h][wave * 32][0]);
      g2l16(Ab + (size_t)(wave * 32 + 16 + srow) * FN + co, &As[h][wave * 32 + 16][0]);
      g2l16(Bb + (size_t)(wave * 32 + srow) * FN + co,      &Bs[h][wave * 32][0]);
      g2l16(Bb + (size_t)(wave * 32 + 16 + srow) * FN + co, &Bs[h][wave * 32 + 16][0]);
    }
    __syncthreads();                  // vmcnt drain + visibility
#pragma unroll
    for (int h = 0; h < 2; h++) {
      bf16x8 af[4], bf[4];
#pragma unroll
      for (int i = 0; i < 4; i++) af[i] = *(bf16x8*)&As[h][wq + i * 16 + r][quad * 8];
#pragma unroll
      for (int j = 0; j < 4; j++) bf[j] = *(bf16x8*)&Bs[h][wk + j * 16 + r][quad * 8];
#pragma unroll
      for (int i = 0; i < 4; i++)
#pragma unroll
        for (int j = 0; j < 4; j++)
          acc[i][j] = __builtin_amdgcn_mfma_f32_16x16x32_bf16(af[i], bf[j], acc[i][j], 0, 0, 0);
    }
  }
  // C/D layout (m89-verified): col = lane&15 (=k), row = quad*4+reg (=q)
#pragma unroll
  for (int i = 0; i < 4; i++)
#pragma unroll
    for (int j = 0; j < 4; j++)
#pragma unroll
      for (int t = 0; t < 4; t++) {
        int qq = qt + wq + i * 16 + quad * 4 + t;
        int kk = kt + wk + j * 16 + r;
        S[(size_t)qq * KN + kk] = (__bf16)acc[i][j][t];
      }
  // Row-sum of exp over this block's 64 k-cols per wave (denominator is
  // UNMASKED sum over all k; partials from the 16 kt-blocks accumulate).
#pragma unroll
  for (int i = 0; i < 4; i++)
#pragma unroll
    for (int t = 0; t < 4; t++) {
      float part = 0.f;
#pragma unroll
      for (int j = 0; j < 4; j++) part += __expf(acc[i][j][t]);
      part += __shfl_xor(part, 1);
      part += __shfl_xor(part, 2);
      part += __shfl_xor(part, 4);
      part += __shfl_xor(part, 8);
      if (r == 0)
        atomicAdd(&sums[(size_t)b * QN + q0 + qt + wq + i * 16 + quad * 4 + t], part);
    }
}

// ---------------------------------------------------------------------------
// Kernel 2: in-place W = attn ? 0 : (exp(S)*inv - (alibi ? 0 : dist*bs))
// PERSISTENT-ROW version: 8 q-rows per block, double-buffered g2l staging in
// the T3 minimum-2-phase shape: STAGE(next); consume(cur); __syncthreads().
// Coords + all per-row scalars loaded once per block (8x fewer setup chains
// than r3's one-row blocks). LDS 40 KB (2 x {S 4K, am 8K, al 8K}) -> 4
// blocks/CU. Per-element math verbatim r3-verified.
// ---------------------------------------------------------------------------
__global__ __launch_bounds__(256) void softmax_w(
    __bf16* __restrict__ Sws,
    const float* __restrict__ cq, const float* __restrict__ ck,
    const int* __restrict__ attn, const int* __restrict__ alibi,
    const float* __restrict__ bsp, const float* __restrict__ sums,
    int b0, int q0, int qchunk) {
  __shared__ __align__(16) __bf16 S_lds[2][KN];   // 2 x 4 KB
  __shared__ __align__(16) int    am_lds[2][KN];  // 2 x 8 KB
  __shared__ __align__(16) int    al_lds[2][KN];  // 2 x 8 KB
  const int tid = threadIdx.x;
  const int lane = tid & 63, wave = tid >> 6;
  const int z = blockIdx.z, b = b0 + z;
  const int qbase = blockIdx.x * 8;        // first local q row of this block
  const float* ckb = ck + (size_t)b * KN * 2;
  // --- per-block k-coord regs (same k columns for all 8 rows) ---
  const int k0g = tid * 4, k1g = 1024 + tid * 4;
  float4 c00 = *(const float4*)(ckb + (size_t)k0g * 2);
  float4 c01 = *(const float4*)(ckb + (size_t)k0g * 2 + 4);
  float4 c10 = *(const float4*)(ckb + (size_t)k1g * 2);
  float4 c11 = *(const float4*)(ckb + (size_t)k1g * 2 + 4);
  const float bs = bsp[0];
  // --- per-row scalars, loaded once (fully unrolled -> static indexing) ---
  float invA[8], qxA[8], qyA[8];
#pragma unroll
  for (int rr = 0; rr < 8; rr++) {
    const int qg = q0 + qbase + rr;
    invA[rr] = 1.0f / sums[(size_t)b * QN + qg];
    qxA[rr]  = cq[((size_t)b * QN + qg) * 2 + 0];
    qyA[rr]  = cq[((size_t)b * QN + qg) * 2 + 1];
  }
  // stage row (qbase+rrw) into buffer bufi: 5 g2l16 per wave (r3 mapping)
#define STAGE_ROW(bufi, rrw)                                                  \
  {                                                                           \
    const __bf16* Sr = Sws + ((size_t)z * qchunk + qbase + (rrw)) * KN;       \
    const int* ar = attn + ((size_t)b * QN + q0 + qbase + (rrw)) * KN;        \
    const int* lr = alibi + ((size_t)b * QN + q0 + qbase + (rrw)) * KN;       \
    g2l16v((const char*)Sr + wave * 1024 + lane * 16,                         \
           (char*)&S_lds[bufi][0] + wave * 1024);                             \
    _Pragma("unroll")                                                         \
    for (int s = 0; s < 2; s++) {                                             \
      const int seg = wave + s * 4;                                           \
      g2l16v((const char*)ar + seg * 1024 + lane * 16,                        \
             (char*)&am_lds[bufi][0] + seg * 1024);                           \
      g2l16v((const char*)lr + seg * 1024 + lane * 16,                        \
             (char*)&al_lds[bufi][0] + seg * 1024);                           \
    }                                                                         \
  }
  STAGE_ROW(0, 0)
  __syncthreads();                         // row 0 staged + visible
#pragma unroll
  for (int rr = 0; rr < 8; rr++) {
    const int cur = rr & 1;
    if (rr + 1 < 8) STAGE_ROW(cur ^ 1, rr + 1)   // issue next-row loads first
    // --- consume row rr from buf[cur] (data synced by prev barrier) ---
    __bf16* Wrow = Sws + ((size_t)z * qchunk + qbase + rr) * KN;
    const float inv = invA[rr], qx = qxA[rr], qy = qyA[rr];
#pragma unroll
    for (int g = 0; g < 2; g++) {
      const int k = g ? k1g : k0g;
      bf16x4v s4 = *(const bf16x4v*)((const char*)&S_lds[cur][0] + (size_t)k * 2);
      int4 am4 = *(const int4*)&am_lds[cur][k];
      int4 al4 = *(const int4*)&al_lds[cur][k];
      float4 ca = g ? c10 : c00;
      float4 cb = g ? c11 : c01;
      float kx[4] = {ca.x, ca.z, cb.x, cb.z};
      float ky[4] = {ca.y, ca.w, cb.y, cb.w};
      int amv[4] = {am4.x, am4.y, am4.z, am4.w};
      int alv[4] = {al4.x, al4.y, al4.z, al4.w};
      bf16x4v w4;
#pragma unroll
      for (int j = 0; j < 4; j++) {
        float p = __expf((float)s4[j]) * inv;
        float dx = qx - kx[j], dy = qy - ky[j];
        float sd = alv[j] ? 0.f : sqrtf(dx * dx + dy * dy) * bs;
        w4[j] = (__bf16)(amv[j] ? 0.f : (p - sd));
      }
      *(bf16x4v*)(Wrow + k) = w4;
    }
    __syncthreads();   // drain stage(rr+1) + stores; buf[cur^1] now ready
  }
#undef STAGE_ROW
}

// ---------------------------------------------------------------------------
// Kernel 3: out[b,q,fv] = sum_k W[q,k] * Vt[fv,k] — bf16 GEMM, BK=64.
// ---------------------------------------------------------------------------
__global__ __launch_bounds__(256) void gemm_w(
    const __bf16* __restrict__ W, const __bf16* __restrict__ Vt,
    float* __restrict__ out, int b0, int q0, int qchunk) {
  __shared__ __align__(16) __bf16 As[2][128][32];  // [q][k]
  __shared__ __align__(16) __bf16 Bs[2][128][32];  // [fv][k]
  const int tid = threadIdx.x;
  const int lane = tid & 63, wave = tid >> 6;
  const int wq = (wave & 1) * 64, wf = (wave >> 1) * 64;
  const int qt = blockIdx.x * 128, ft = blockIdx.y * 128;
  const int z = blockIdx.z, b = b0 + z;
  const __bf16* Ab = W + ((size_t)z * qchunk + qt) * KN;
  const __bf16* Bb = Vt + ((size_t)b * FVN + ft) * KN;
  const int srow = lane >> 2;
  const int scol = (lane & 3) * 8;
  const int r = lane & 15, quad = lane >> 4;
  f32x4 acc[4][4] = {};
  for (int k0 = 0; k0 < KN; k0 += 64) {
    __syncthreads();
#pragma unroll
    for (int h = 0; h < 2; h++) {
      const int co = k0 + h * 32 + scol;
      g2l16(Ab + (size_t)(wave * 32 + srow) * KN + co,      &As[h][wave * 32][0]);
      g2l16(Ab + (size_t)(wave * 32 + 16 + srow) * KN + co, &As[h][wave * 32 + 16][0]);
      g2l16(Bb + (size_t)(wave * 32 + srow) * KN + co,      &Bs[h][wave * 32][0]);
      g2l16(Bb + (size_t)(wave * 32 + 16 + srow) * KN + co, &Bs[h][wave * 32 + 16][0]);
    }
    __syncthreads();
#pragma unroll
    for (int h = 0; h < 2; h++) {
      bf16x8 af[4], bf[4];
#pragma unroll
      for (int i = 0; i < 4; i++) af[i] = *(bf16x8*)&As[h][wq + i * 16 + r][quad * 8];
#pragma unroll
      for (int j = 0; j < 4; j++) bf[j] = *(bf16x8*)&Bs[h][wf + j * 16 + r][quad * 8];
#pragma unroll
      for (int i = 0; i < 4; i++)
#pragma unroll
        for (int j = 0; j < 4; j++)
          acc[i][j] = __builtin_amdgcn_mfma_f32_16x16x32_bf16(af[i], bf[j], acc[i][j], 0, 0, 0);
    }
  }
#pragma unroll
  for (int i = 0; i < 4; i++)
#pragma unroll
    for (int j = 0; j < 4; j++)
#pragma unroll
      for (int t = 0; t < 4; t++) {
        int qq = q0 + qt + wq + i * 16 + quad * 4 + t;
        int fv = ft + wf + j * 16 + r;
        out[((size_t)b * QN + qq) * FVN + fv] = acc[i][j][t];
      }
}

// ---------------------------------------------------------------------------
extern "C" void kernel_launch(void* const* d_in, const int* in_sizes, int n_in,
                              void* d_out, int out_size, void* d_ws, size_t ws_size,
                              hipStream_t stream) {
  (void)in_sizes; (void)n_in; (void)out_size;
  const float* qm   = (const float*)d_in[0];
  const float* km   = (const float*)d_in[1];
  const float* vm   = (const float*)d_in[2];
  const float* cq   = (const float*)d_in[3];
  const float* ck   = (const float*)d_in[4];
  const int*   attn = (const int*)d_in[5];
  const int*   alibi= (const int*)d_in[6];
  const float* bsp  = (const float*)d_in[7];
  float* out = (float*)d_out;

  // ws layout: [qb][kb][Vt][sums f32] fixed + [S/W: nb*qc*KN bf16]
  __bf16* qb  = (__bf16*)d_ws;
  __bf16* kb  = qb + (size_t)BN * QN * FN;
  __bf16* Vt  = kb + (size_t)BN * KN * FN;
  float*  sums = (float*)(Vt + (size_t)BN * FVN * KN);
  __bf16* Sws = (__bf16*)(sums + (size_t)BN * QN);
  const size_t fixed = ((size_t)BN * QN * FN + (size_t)BN * KN * FN +
                        (size_t)BN * FVN * KN) * 2 + (size_t)BN * QN * 4;
  int nb = BN, qc = QN;
  while (nb > 1 && fixed + (size_t)nb * qc * KN * 2 > ws_size) nb >>= 1;
  while (qc > 128 && fixed + (size_t)nb * qc * KN * 2 > ws_size) qc >>= 1;

  prep<<<dim3((BN * QN * FN) / 2048, 4), 256, 0, stream>>>(qm, km, vm, qb, kb, Vt, sums);
  for (int b0 = 0; b0 < BN; b0 += nb) {
    for (int q0 = 0; q0 < QN; q0 += qc) {
      gemm_s<<<dim3(qc / 128, KN / 128, nb), 256, 0, stream>>>(qb, kb, Sws, sums, b0, q0, qc);
      softmax_w<<<dim3(qc / 8, 1, nb), 256, 0, stream>>>(Sws, cq, ck, attn, alibi, bsp,
                                                         sums, b0, q0, qc);
      gemm_w<<<dim3(qc / 128, FVN / 128, nb), 256, 0, stream>>>(Sws, Vt, out, b0, q0, qc);
    }
  }
}